// Round 3
// baseline (200.939 us; speedup 1.0000x reference)
//
#include <hip/hip_runtime.h>
#include <hip/hip_bf16.h>
#include <cstdint>

// ---------- types ----------
typedef __attribute__((ext_vector_type(8)))  short s8b;   // 8 bf16
typedef __attribute__((ext_vector_type(4)))  short s4b;   // 4 bf16
typedef __attribute__((ext_vector_type(16))) float f16v;  // 32x32 MFMA acc

#define MFMA32(a,b,c) __builtin_amdgcn_mfma_f32_32x32x16_bf16((a),(b),(c),0,0,0)

#define OLDN   16384
#define NEWB   2048
#define DHEAD  256
#define NTOTAL 18432
#define EXPSC  0.09016844005556021f   // (1/sqrt(256)) * log2(e)

// LDS strides (shorts); dword strides 132 / 20 are ==4 mod 8 -> bank-even column reads
#define KSTR  264
#define VSTR  40

static __device__ __forceinline__ short f2bf(float f) {
    unsigned u = __float_as_uint(f);
    unsigned r = (u + 0x7fffu + ((u >> 16) & 1u)) >> 16;   // RNE
    return (short)r;
}

// ---------- kernel 1: fp32 K/V (+ new k/v) -> bf16 copies in ws ----------
__global__ void cvt_kernel(const float* __restrict__ Kc, const float* __restrict__ kn,
                           const float* __restrict__ Vc, const float* __restrict__ vn,
                           s8b* __restrict__ Kb, s8b* __restrict__ Vb) {
    int idx8 = blockIdx.x * 256 + threadIdx.x;
    int idx  = idx8 * 8;
    int row  = idx >> 8;
    int col  = idx & 255;
    const float* src;
    if (blockIdx.y == 0)
        src = (row < OLDN) ? (Kc + (size_t)row * DHEAD + col)
                           : (kn + (size_t)(row - OLDN) * DHEAD + col);
    else
        src = (row < OLDN) ? (Vc + (size_t)row * DHEAD + col)
                           : (vn + (size_t)(row - OLDN) * DHEAD + col);
    float4 f0 = *(const float4*)src;
    float4 f1 = *(const float4*)(src + 4);
    s8b o;
    o[0]=f2bf(f0.x); o[1]=f2bf(f0.y); o[2]=f2bf(f0.z); o[3]=f2bf(f0.w);
    o[4]=f2bf(f1.x); o[5]=f2bf(f1.y); o[6]=f2bf(f1.z); o[7]=f2bf(f1.w);
    (blockIdx.y == 0 ? Kb : Vb)[idx8] = o;
}

// ---------- kernel 2: flash attention, S^T/O^T formulation, 32x32x16 MFMA ----------
// grid = 16 * SPLIT blocks of 256 threads; wave owns 32 q-rows (BLOCK_Q = 128)
__global__ __launch_bounds__(256, 2)
void attn_kernel(const float* __restrict__ q,
                 const short* __restrict__ Kb, const short* __restrict__ Vb,
                 float* __restrict__ OP, float* __restrict__ L, int SPLIT) {
    __shared__ short K_lds[32 * KSTR];        // [key][d]      (natural)
    __shared__ short Vt_lds[DHEAD * VSTR];    // [d][slot]     (slot = permuted key)

    const int bx   = blockIdx.x;
    const int s    = bx % SPLIT;
    const int qb   = bx / SPLIT;
    const int q0   = qb * 128;
    const int tid  = threadIdx.x;
    const int w    = tid >> 6;
    const int lane = tid & 63;
    const int lc   = lane & 31;     // q-column (B/C operand n-index), key row for A(K)
    const int h    = lane >> 5;

    // --- Q fragments (B-operand of S^T): lane holds Q[q0+32w+lc][16c + 8h + j]
    s8b qf[16];
    {
        const int qrow = q0 + 32 * w + lc;
        const float* qp = q + (size_t)qrow * DHEAD + 8 * h;
#pragma unroll
        for (int c = 0; c < 16; ++c) {
            float4 f0 = *(const float4*)(qp + 16 * c);
            float4 f1 = *(const float4*)(qp + 16 * c + 4);
            s8b o;
            o[0]=f2bf(f0.x); o[1]=f2bf(f0.y); o[2]=f2bf(f0.z); o[3]=f2bf(f0.w);
            o[4]=f2bf(f1.x); o[5]=f2bf(f1.y); o[6]=f2bf(f1.z); o[7]=f2bf(f1.w);
            qf[c] = o;
        }
    }

    f16v acc[8];   // O^T accumulator: acc[c] covers d = 32c..32c+31 (C-layout), q = lc
#pragma unroll
    for (int c = 0; c < 8; ++c)
#pragma unroll
        for (int r = 0; r < 16; ++r) acc[c][r] = 0.f;
    float lsum = 0.f;

    // --- staging constants ---
    const int krow = tid >> 3;            // K LDS row (= key index, natural)
    const int kcb  = (tid & 7) * 8;       // K col offset (shorts)
    const int va   = tid & 3;             // V slot-group: slots 8va..8va+7
    const int vd   = (tid >> 2) * 4;      // V dim base (4 dims)
    const int vkb  = 16 * (va >> 1) + 4 * (va & 1);   // key base of this slot-group

    // --- key-tile range for this split ---
    const int nt_total = (OLDN + q0 + 128) >> 5;
    const int tb  = nt_total / SPLIT;
    const int rem = nt_total % SPLIT;
    const int t0  = s * tb + (s < rem ? s : rem);
    const int tcnt = tb + (s < rem ? 1 : 0);

    const int qbase = OLDN + q0 + 32 * w;      // min query row of this wave

    for (int t = t0; t < t0 + tcnt; ++t) {
        const int kk = t << 5;
        __syncthreads();
        // ---- stage K tile (natural [key][d], b128 writes) ----
        {
            const s8b* src = (const s8b*)(Kb + (size_t)(kk + krow) * DHEAD + kcb);
            short* dst = &K_lds[krow * KSTR + kcb];
#pragma unroll
            for (int i = 0; i < 4; ++i)
                *(s8b*)(dst + i * 64) = src[i * 8];
        }
        // ---- stage V transposed into permuted slots: Vt[d][slot] ----
        // slot 8va+j  <->  key vkb + (j&3) + 8*(j>>2)
        {
            s4b ld[8];
#pragma unroll
            for (int j = 0; j < 8; ++j)
                ld[j] = *(const s4b*)(Vb + (size_t)(kk + vkb + (j & 3) + 8 * (j >> 2)) * DHEAD + vd);
#pragma unroll
            for (int r = 0; r < 4; ++r) {
                s8b o;
#pragma unroll
                for (int j = 0; j < 8; ++j) o[j] = ld[j][r];
                *(s8b*)&Vt_lds[(vd + r) * VSTR + 8 * va] = o;
            }
        }
        __syncthreads();

        // ---- S^T = K Q^T : A = K tile (LDS), B = Q (regs) ----
        f16v sacc;
#pragma unroll
        for (int r = 0; r < 16; ++r) sacc[r] = 0.f;
#pragma unroll
        for (int c = 0; c < 16; ++c) {
            s8b kf = *(const s8b*)&K_lds[lc * KSTR + 16 * c + 8 * h];
            sacc = MFMA32(kf, qf[c], sacc);
        }

        // ---- p = exp2(score*c), causal mask near diagonal; pack into P^T B-frags ----
        const bool domask = (kk + 31 > qbase);
        float e[16];
#pragma unroll
        for (int r = 0; r < 16; ++r) {
            float ev = __builtin_exp2f(sacc[r] * EXPSC);
            if (domask) {
                int key = kk + (r & 3) + 8 * (r >> 2) + 4 * h;   // C-layout row
                if (key > qbase + lc) ev = 0.f;
            }
            e[r] = ev;
            lsum += ev;
        }
        s8b pf0, pf1;
#pragma unroll
        for (int j = 0; j < 8; ++j) { pf0[j] = f2bf(e[j]); pf1[j] = f2bf(e[8 + j]); }

        // ---- O^T += V^T P^T : A = V^T slots (LDS), B = pf0/pf1 (regs) ----
#pragma unroll
        for (int c = 0; c < 8; ++c) {
            const short* vrow = &Vt_lds[(32 * c + lc) * VSTR];
            s8b v0 = *(const s8b*)(vrow + 8 * h);        // slots 0..15
            s8b v1 = *(const s8b*)(vrow + 16 + 8 * h);   // slots 16..31
            acc[c] = MFMA32(v0, pf0, acc[c]);
            acc[c] = MFMA32(v1, pf1, acc[c]);
        }
    }

    // ---- finalize l: other lane-half holds the other 16 keys of each q-column ----
    lsum += __shfl_xor(lsum, 32);

    // ---- write unnormalized partials + l ----
    const int qrow = q0 + 32 * w + lc;
    const size_t sbase = (size_t)s * NEWB;
    float* op_row = OP + (sbase + qrow) * DHEAD;
#pragma unroll
    for (int c = 0; c < 8; ++c)
#pragma unroll
        for (int g = 0; g < 4; ++g) {
            float4 o = {acc[c][4 * g], acc[c][4 * g + 1], acc[c][4 * g + 2], acc[c][4 * g + 3]};
            *(float4*)(op_row + 32 * c + 8 * g + 4 * h) = o;
        }
    if (h == 0)
        L[sbase + qrow] = lsum;
}

// ---------- kernel 3: split-K combine ----------
__global__ void combine_kernel(const float* __restrict__ OP, const float* __restrict__ L,
                               float* __restrict__ out, int SPLIT) {
    const int row = blockIdx.x;
    const int col = threadIdx.x;
    float num = 0.f, den = 0.f;
    for (int s = 0; s < SPLIT; ++s) {
        size_t r = (size_t)s * NEWB + row;
        num += OP[r * DHEAD + col];
        den += L[r];
    }
    out[(size_t)row * DHEAD + col] = num / den;
}

// ---------- launch ----------
extern "C" void kernel_launch(void* const* d_in, const int* in_sizes, int n_in,
                              void* d_out, int out_size, void* d_ws, size_t ws_size,
                              hipStream_t stream) {
    const float* q  = (const float*)d_in[0];
    const float* kn = (const float*)d_in[1];
    const float* vn = (const float*)d_in[2];
    const float* Kc = (const float*)d_in[3];
    const float* Vc = (const float*)d_in[4];
    float* out = (float*)d_out;

    char* ws = (char*)d_ws;
    const size_t KB_BYTES = (size_t)NTOTAL * DHEAD * 2;
    short* Kb = (short*)(ws);
    short* Vb = (short*)(ws + KB_BYTES);
    const size_t PART_BASE = 2 * KB_BYTES;

    const size_t per_split = (size_t)NEWB * DHEAD * 4 + (size_t)NEWB * 4;
    size_t avail = (ws_size > PART_BASE) ? (ws_size - PART_BASE) : 0;
    int SPLIT = (int)(avail / per_split);
    if (SPLIT > 32) SPLIT = 32;    // grid 512 = 2 blocks/CU
    if (SPLIT < 1)  SPLIT = 1;

    float* OP = (float*)(ws + PART_BASE);
    float* L  = (float*)(ws + PART_BASE + (size_t)SPLIT * NEWB * DHEAD * 4);

    cvt_kernel<<<dim3(NTOTAL * DHEAD / (256 * 8), 2), 256, 0, stream>>>(Kc, kn, Vc, vn,
                                                                        (s8b*)Kb, (s8b*)Vb);
    attn_kernel<<<16 * SPLIT, 256, 0, stream>>>(q, Kb, Vb, OP, L, SPLIT);
    combine_kernel<<<NEWB, 256, 0, stream>>>(OP, L, out, SPLIT);
}

// Round 4
// 187.238 us; speedup vs baseline: 1.0732x; 1.0732x over previous
//
#include <hip/hip_runtime.h>
#include <hip/hip_bf16.h>
#include <cstdint>

typedef __attribute__((ext_vector_type(8)))  short s8b;     // 8 bf16
typedef __attribute__((ext_vector_type(4)))  short s4b;     // 4 bf16
typedef __attribute__((ext_vector_type(16))) float f16v;    // 32x32 MFMA acc
typedef __attribute__((ext_vector_type(4)))  unsigned u4v;

#define MFMA32(a,b,c) __builtin_amdgcn_mfma_f32_32x32x16_bf16((a),(b),(c),0,0,0)

#define OLDN   16384
#define NEWB   2048
#define DHEAD  256
#define NTOTAL 18432
#define NTILES 576                      // NTOTAL / 32
#define EXPSC  0.09016844005556021f    // (1/sqrt(256)) * log2(e)

static __device__ __forceinline__ short f2bf(float f) {
    unsigned u = __float_as_uint(f);
    unsigned r = (u + 0x7fffu + ((u >> 16) & 1u)) >> 16;   // RNE
    return (short)r;
}
// V slot permutation: slot s -> key within 32-tile (matches S^T C-layout reg order)
static __device__ __forceinline__ int slot_key(int s) {
    return (s & 3) + 8 * ((s >> 2) & 1) + 4 * ((s >> 3) & 1) + 16 * (s >> 4);
}

// ---------- kernel 1: build fragment-order bf16 tile copies ----------
// Ksw[t][c][l] (16B chunk) = K[32t + (l&31)][16c + 8*(l>>5) + j]  (j=0..7)
// Vsw[t][b][l] (16B chunk) = V[32t + slot_key(16*(b&1)+8*(l>>5)+j)][32*(b>>1) + (l&31)]
__global__ void cvt_kernel(const float* __restrict__ Kc, const float* __restrict__ kn,
                           const float* __restrict__ Vc, const float* __restrict__ vn,
                           s8b* __restrict__ Ksw, s8b* __restrict__ Vsw) {
    const int t   = blockIdx.x;
    const int tid = threadIdx.x;
    if (blockIdx.y == 0) {
#pragma unroll
        for (int i = 0; i < 4; ++i) {
            int chunk = tid + 256 * i;            // = b*64 + l
            int l = chunk & 63;
            int b = chunk >> 6;
            int row = 32 * t + (l & 31);
            int col = 16 * b + 8 * (l >> 5);
            const float* src = (row < OLDN) ? Kc + (size_t)row * DHEAD + col
                                            : kn + (size_t)(row - OLDN) * DHEAD + col;
            float4 f0 = *(const float4*)src;
            float4 f1 = *(const float4*)(src + 4);
            s8b o;
            o[0]=f2bf(f0.x); o[1]=f2bf(f0.y); o[2]=f2bf(f0.z); o[3]=f2bf(f0.w);
            o[4]=f2bf(f1.x); o[5]=f2bf(f1.y); o[6]=f2bf(f1.z); o[7]=f2bf(f1.w);
            Ksw[(size_t)t * 1024 + chunk] = o;
        }
    } else {
#pragma unroll
        for (int i = 0; i < 4; ++i) {
            int chunk = tid + 256 * i;
            int l = chunk & 63;
            int b = chunk >> 6;
            int m = 32 * (b >> 1) + (l & 31);
            int sbase = 16 * (b & 1) + 8 * (l >> 5);
            s8b o;
#pragma unroll
            for (int j = 0; j < 8; ++j) {
                int row = 32 * t + slot_key(sbase + j);
                float v = (row < OLDN) ? Vc[(size_t)row * DHEAD + m]
                                       : vn[(size_t)(row - OLDN) * DHEAD + m];
                o[j] = f2bf(v);
            }
            Vsw[(size_t)t * 1024 + chunk] = o;
        }
    }
}

// ---------- kernel 2: flash attention, K from global (L1-dedup), V via LDS ----------
// grid = 16 * SPLIT blocks of 256 threads; wave owns 32 q-rows (BLOCK_Q = 128)
__global__ __launch_bounds__(256, 2)
void attn_kernel(const float* __restrict__ q,
                 const s8b* __restrict__ Ksw, const s8b* __restrict__ Vsw,
                 short* __restrict__ OPb, float* __restrict__ L, int SPLIT) {
    __shared__ short V_lds[16 * 512];   // 16 fragment blocks x 64 lanes x 8 bf16 = 16 KB

    const int bx   = blockIdx.x;
    const int s    = bx % SPLIT;
    const int qb   = bx / SPLIT;
    const int q0   = qb * 128;
    const int tid  = threadIdx.x;
    const int w    = tid >> 6;
    const int lane = tid & 63;
    const int lc   = lane & 31;
    const int h    = lane >> 5;

    // Q fragments (B-operand), EXPSC folded in
    s8b qf[16];
    {
        const int qrow = q0 + 32 * w + lc;
        const float* qp = q + (size_t)qrow * DHEAD + 8 * h;
#pragma unroll
        for (int c = 0; c < 16; ++c) {
            float4 f0 = *(const float4*)(qp + 16 * c);
            float4 f1 = *(const float4*)(qp + 16 * c + 4);
            s8b o;
            o[0]=f2bf(f0.x*EXPSC); o[1]=f2bf(f0.y*EXPSC); o[2]=f2bf(f0.z*EXPSC); o[3]=f2bf(f0.w*EXPSC);
            o[4]=f2bf(f1.x*EXPSC); o[5]=f2bf(f1.y*EXPSC); o[6]=f2bf(f1.z*EXPSC); o[7]=f2bf(f1.w*EXPSC);
            qf[c] = o;
        }
    }

    f16v acc[8];
#pragma unroll
    for (int c = 0; c < 8; ++c)
#pragma unroll
        for (int r = 0; r < 16; ++r) acc[c][r] = 0.f;
    float lsum = 0.f;

    const int nt_total = (OLDN + q0 + 128) >> 5;
    const int tb  = nt_total / SPLIT;
    const int rem = nt_total % SPLIT;
    const int t0  = s * tb + (s < rem ? s : rem);
    const int tcnt = tb + (s < rem ? 1 : 0);
    const int qbase = OLDN + q0 + 32 * w;

    const s8b* kp = Ksw + (size_t)t0 * 1024 + lane;                 // + c*64 per block
    const s8b* vp = Vsw + (size_t)t0 * 1024 + (size_t)(4 * w) * 64 + lane;
    short* vlds_w = &V_lds[(4 * w) * 512 + lane * 8];               // this wave's 4 dst blocks
    const short* vlds_r = &V_lds[lane * 8];                         // + block*512 on read

    for (int t = t0; t < t0 + tcnt; ++t, kp += 1024, vp += 1024) {
        const int kk = t << 5;

        // (A) V tile -> regs (4 x b128 per wave)
        s8b vstage[4];
#pragma unroll
        for (int i = 0; i < 4; ++i) vstage[i] = vp[i * 64];

        // (B) S^T = K Q^T, two independent chains, K straight from global (L1)
        f16v sacc0, sacc1;
#pragma unroll
        for (int r = 0; r < 16; ++r) { sacc0[r] = 0.f; sacc1[r] = 0.f; }
#pragma unroll
        for (int c = 0; c < 8; ++c) {
            s8b k0 = kp[(2 * c) * 64];
            s8b k1 = kp[(2 * c + 1) * 64];
            sacc0 = MFMA32(k0, qf[2 * c],     sacc0);
            sacc1 = MFMA32(k1, qf[2 * c + 1], sacc1);
        }

        // (C) p = exp2(s), mask near diagonal, trunc-pack into P^T B-frags
        const bool domask = (kk + 31 > qbase);
        unsigned pk[8];
#pragma unroll
        for (int i = 0; i < 8; ++i) {
            const int r0 = 2 * i, r1 = 2 * i + 1;
            float ev0 = __builtin_exp2f(sacc0[r0] + sacc1[r0]);
            float ev1 = __builtin_exp2f(sacc0[r1] + sacc1[r1]);
            if (domask) {
                if (kk + (r0 & 3) + 8 * (r0 >> 2) + 4 * h > qbase + lc) ev0 = 0.f;
                if (kk + (r1 & 3) + 8 * (r1 >> 2) + 4 * h > qbase + lc) ev1 = 0.f;
            }
            lsum += ev0 + ev1;
            pk[i] = __builtin_amdgcn_perm(__float_as_uint(ev1), __float_as_uint(ev0), 0x07060302u);
        }
        s8b pf0 = __builtin_bit_cast(s8b, (u4v){pk[0], pk[1], pk[2], pk[3]});
        s8b pf1 = __builtin_bit_cast(s8b, (u4v){pk[4], pk[5], pk[6], pk[7]});

        // (D) stage V tile (conflict-free b128, fragment order)
#pragma unroll
        for (int i = 0; i < 4; ++i) *(s8b*)(vlds_w + i * 512) = vstage[i];
        __syncthreads();

        // (F) O^T += V^T P^T
#pragma unroll
        for (int c = 0; c < 8; ++c) {
            s8b v0 = *(const s8b*)(vlds_r + (2 * c) * 512);
            s8b v1 = *(const s8b*)(vlds_r + (2 * c + 1) * 512);
            acc[c] = MFMA32(v0, pf0, acc[c]);
            acc[c] = MFMA32(v1, pf1, acc[c]);
        }
        __syncthreads();
    }

    // finalize l (other half-lane holds the other 16 keys of each q-column)
    lsum += __shfl_xor(lsum, 32);

    // write bf16 unnormalized partials + fp32 l
    const int qrow = q0 + 32 * w + lc;
    const size_t sbase = (size_t)s * NEWB;
    short* op_row = OPb + (sbase + qrow) * DHEAD;
#pragma unroll
    for (int c = 0; c < 8; ++c)
#pragma unroll
        for (int g = 0; g < 4; ++g) {
            s4b o4;
            o4[0] = f2bf(acc[c][4 * g]);
            o4[1] = f2bf(acc[c][4 * g + 1]);
            o4[2] = f2bf(acc[c][4 * g + 2]);
            o4[3] = f2bf(acc[c][4 * g + 3]);
            *(s4b*)(op_row + 32 * c + 8 * g + 4 * h) = o4;
        }
    if (h == 0) L[sbase + qrow] = lsum;
}

// ---------- kernel 3: split-K combine (bf16 partials, fp32 l) ----------
__global__ void combine_kernel(const short* __restrict__ OPb, const float* __restrict__ L,
                               float* __restrict__ out, int SPLIT) {
    const int row = blockIdx.x;
    const int col = threadIdx.x;
    float num = 0.f, den = 0.f;
    for (int s = 0; s < SPLIT; ++s) {
        size_t r = (size_t)s * NEWB + row;
        unsigned u = (unsigned)(unsigned short)OPb[r * DHEAD + col];
        num += __uint_as_float(u << 16);
        den += L[r];
    }
    out[(size_t)row * DHEAD + col] = num / den;
}

// ---------- launch ----------
extern "C" void kernel_launch(void* const* d_in, const int* in_sizes, int n_in,
                              void* d_out, int out_size, void* d_ws, size_t ws_size,
                              hipStream_t stream) {
    const float* q  = (const float*)d_in[0];
    const float* kn = (const float*)d_in[1];
    const float* vn = (const float*)d_in[2];
    const float* Kc = (const float*)d_in[3];
    const float* Vc = (const float*)d_in[4];
    float* out = (float*)d_out;

    char* ws = (char*)d_ws;
    const size_t KB_BYTES = (size_t)NTOTAL * DHEAD * 2;   // 9,437,184 per array
    s8b* Ksw = (s8b*)(ws);
    s8b* Vsw = (s8b*)(ws + KB_BYTES);
    const size_t PART_BASE = 2 * KB_BYTES;

    const size_t per_split = (size_t)NEWB * DHEAD * 2 + (size_t)NEWB * 4;  // bf16 OP + fp32 L
    size_t avail = (ws_size > PART_BASE) ? (ws_size - PART_BASE) : 0;
    int SPLIT = (int)(avail / per_split);
    if (SPLIT > 32) SPLIT = 32;    // grid 512 = 2 blocks/CU
    if (SPLIT < 1)  SPLIT = 1;

    short* OPb = (short*)(ws + PART_BASE);
    float* L   = (float*)(ws + PART_BASE + (size_t)SPLIT * NEWB * DHEAD * 2);

    cvt_kernel<<<dim3(NTILES, 2), 256, 0, stream>>>(Kc, kn, Vc, vn, Ksw, Vsw);
    attn_kernel<<<16 * SPLIT, 256, 0, stream>>>(q, Ksw, Vsw, OPb, L, SPLIT);
    combine_kernel<<<NEWB, 256, 0, stream>>>(OPb, L, out, SPLIT);
}

// Round 5
// 168.572 us; speedup vs baseline: 1.1920x; 1.1107x over previous
//
#include <hip/hip_runtime.h>
#include <hip/hip_bf16.h>
#include <cstdint>

typedef __attribute__((ext_vector_type(8)))  short s8b;     // 8 bf16
typedef __attribute__((ext_vector_type(4)))  short s4b;     // 4 bf16
typedef __attribute__((ext_vector_type(16))) float f16v;    // 32x32 MFMA acc
typedef __attribute__((ext_vector_type(4)))  unsigned u4v;

#define MFMA32(a,b,c) __builtin_amdgcn_mfma_f32_32x32x16_bf16((a),(b),(c),0,0,0)

#define OLDN   16384
#define NEWB   2048
#define DHEAD  256
#define NTOTAL 18432
#define NTILES 576                      // NTOTAL / 32
#define EXPSC  0.09016844005556021f    // (1/sqrt(256)) * log2(e)

static __device__ __forceinline__ short f2bf(float f) {
    unsigned u = __float_as_uint(f);
    unsigned r = (u + 0x7fffu + ((u >> 16) & 1u)) >> 16;   // RNE
    return (short)r;
}
// V slot permutation: slot s -> key within 32-tile (matches S^T C-layout reg order)
static __device__ __forceinline__ int slot_key(int s) {
    return (s & 3) + 8 * ((s >> 2) & 1) + 4 * ((s >> 3) & 1) + 16 * (s >> 4);
}

// async global -> LDS, 16 B per lane (global_load_lds_dwordx4)
static __device__ __forceinline__ void dma16(const void* g, void* l) {
    __builtin_amdgcn_global_load_lds((const __attribute__((address_space(1))) unsigned int*)g,
                                     (__attribute__((address_space(3))) unsigned int*)l,
                                     16, 0, 0);
}

// ---------- kernel 1: build fragment-order bf16 tile copies ----------
// Ksw[t][c][l] (16B chunk) = K[32t + (l&31)][16c + 8*(l>>5) + j]  (j=0..7)
// Vsw[t][b][l] (16B chunk) = V[32t + slot_key(16*(b&1)+8*(l>>5)+j)][32*(b>>1) + (l&31)]
__global__ void cvt_kernel(const float* __restrict__ Kc, const float* __restrict__ kn,
                           const float* __restrict__ Vc, const float* __restrict__ vn,
                           s8b* __restrict__ Ksw, s8b* __restrict__ Vsw) {
    const int t   = blockIdx.x;
    const int tid = threadIdx.x;
    if (blockIdx.y == 0) {
#pragma unroll
        for (int i = 0; i < 4; ++i) {
            int chunk = tid + 256 * i;            // = b*64 + l
            int l = chunk & 63;
            int b = chunk >> 6;
            int row = 32 * t + (l & 31);
            int col = 16 * b + 8 * (l >> 5);
            const float* src = (row < OLDN) ? Kc + (size_t)row * DHEAD + col
                                            : kn + (size_t)(row - OLDN) * DHEAD + col;
            float4 f0 = *(const float4*)src;
            float4 f1 = *(const float4*)(src + 4);
            s8b o;
            o[0]=f2bf(f0.x); o[1]=f2bf(f0.y); o[2]=f2bf(f0.z); o[3]=f2bf(f0.w);
            o[4]=f2bf(f1.x); o[5]=f2bf(f1.y); o[6]=f2bf(f1.z); o[7]=f2bf(f1.w);
            Ksw[(size_t)t * 1024 + chunk] = o;
        }
    } else {
#pragma unroll
        for (int i = 0; i < 4; ++i) {
            int chunk = tid + 256 * i;
            int l = chunk & 63;
            int b = chunk >> 6;
            int m = 32 * (b >> 1) + (l & 31);
            int sbase = 16 * (b & 1) + 8 * (l >> 5);
            s8b o;
#pragma unroll
            for (int j = 0; j < 8; ++j) {
                int row = 32 * t + slot_key(sbase + j);
                float v = (row < OLDN) ? Vc[(size_t)row * DHEAD + m]
                                       : vn[(size_t)(row - OLDN) * DHEAD + m];
                o[j] = f2bf(v);
            }
            Vsw[(size_t)t * 1024 + chunk] = o;
        }
    }
}

// ---------- kernel 2: flash attention, DMA double-buffered K+V tiles ----------
// grid = 16 * SPLIT blocks of 256 threads; wave owns 32 q-rows (BLOCK_Q = 128)
// LDS buffer layout (shorts): [buf][ K chunks 0..15 | V chunks 0..15 ], chunk = 512 shorts
__global__ __launch_bounds__(256, 2)
void attn_kernel(const float* __restrict__ q,
                 const s8b* __restrict__ Ksw, const s8b* __restrict__ Vsw,
                 short* __restrict__ OPb, float* __restrict__ L, int SPLIT) {
    __shared__ short smem[2 * 16384];   // 2 x 32 KB

    const int bx   = blockIdx.x;
    const int s    = bx % SPLIT;
    const int qb   = bx / SPLIT;
    const int q0   = qb * 128;
    const int tid  = threadIdx.x;
    const int w    = tid >> 6;
    const int lane = tid & 63;
    const int lc   = lane & 31;
    const int h    = lane >> 5;

    // Q fragments (B-operand), EXPSC folded in
    s8b qf[16];
    {
        const int qrow = q0 + 32 * w + lc;
        const float* qp = q + (size_t)qrow * DHEAD + 8 * h;
#pragma unroll
        for (int c = 0; c < 16; ++c) {
            float4 f0 = *(const float4*)(qp + 16 * c);
            float4 f1 = *(const float4*)(qp + 16 * c + 4);
            s8b o;
            o[0]=f2bf(f0.x*EXPSC); o[1]=f2bf(f0.y*EXPSC); o[2]=f2bf(f0.z*EXPSC); o[3]=f2bf(f0.w*EXPSC);
            o[4]=f2bf(f1.x*EXPSC); o[5]=f2bf(f1.y*EXPSC); o[6]=f2bf(f1.z*EXPSC); o[7]=f2bf(f1.w*EXPSC);
            qf[c] = o;
        }
    }

    f16v acc[8];
#pragma unroll
    for (int c = 0; c < 8; ++c)
#pragma unroll
        for (int r = 0; r < 16; ++r) acc[c][r] = 0.f;
    float lsum = 0.f;

    const int nt_total = (OLDN + q0 + 128) >> 5;
    const int tb  = nt_total / SPLIT;
    const int rem = nt_total % SPLIT;
    const int t0  = s * tb + (s < rem ? s : rem);
    const int tcnt = tb + (s < rem ? 1 : 0);
    const int tend = t0 + tcnt;
    const int qbase = OLDN + q0 + 32 * w;

    // staging: wave w covers segments 8w..8w+7 (segs 0..15 = K chunks, 16..31 = V chunks)
    const s8b* gseg = (w < 2) ? (Ksw + (size_t)(8 * w) * 64 + lane)
                              : (Vsw + (size_t)(8 * (w - 2)) * 64 + lane);
    short* lseg = &smem[(8 * w) * 512 + lane * 8];            // + buf*16384

    // prologue: stage t0 -> buf0, t0+1 -> buf1
    {
        const s8b* g0 = gseg + (size_t)t0 * 1024;
#pragma unroll
        for (int i = 0; i < 8; ++i) dma16(g0 + i * 64, lseg + i * 512);
        const int t1 = (t0 + 1 < tend) ? t0 + 1 : t0;
        const s8b* g1 = gseg + (size_t)t1 * 1024;
#pragma unroll
        for (int i = 0; i < 8; ++i) dma16(g1 + i * 64, lseg + 16384 + i * 512);
    }
    __syncthreads();

    int cur = 0;
    for (int t = t0; t < tend; ++t, cur ^= 1) {
        const int kk = t << 5;
        const short* Kbuf = &smem[cur * 16384 + lane * 8];
        const short* Vbuf = Kbuf + 8192;

        // (A) S^T = K Q^T, two independent chains, K frags from LDS
        f16v sacc0, sacc1;
#pragma unroll
        for (int r = 0; r < 16; ++r) { sacc0[r] = 0.f; sacc1[r] = 0.f; }
#pragma unroll
        for (int c = 0; c < 8; ++c) {
            s8b k0 = *(const s8b*)(Kbuf + (2 * c) * 512);
            s8b k1 = *(const s8b*)(Kbuf + (2 * c + 1) * 512);
            sacc0 = MFMA32(k0, qf[2 * c],     sacc0);
            sacc1 = MFMA32(k1, qf[2 * c + 1], sacc1);
        }

        // (B) p = exp2(s), mask near diagonal, trunc-pack into P^T B-frags
        const bool domask = (kk + 31 > qbase);
        unsigned pk[8];
#pragma unroll
        for (int i = 0; i < 8; ++i) {
            const int r0 = 2 * i, r1 = 2 * i + 1;
            float ev0 = __builtin_exp2f(sacc0[r0] + sacc1[r0]);
            float ev1 = __builtin_exp2f(sacc0[r1] + sacc1[r1]);
            if (domask) {
                if (kk + (r0 & 3) + 8 * (r0 >> 2) + 4 * h > qbase + lc) ev0 = 0.f;
                if (kk + (r1 & 3) + 8 * (r1 >> 2) + 4 * h > qbase + lc) ev1 = 0.f;
            }
            lsum += ev0 + ev1;
            pk[i] = __builtin_amdgcn_perm(__float_as_uint(ev1), __float_as_uint(ev0), 0x07060302u);
        }
        s8b pf0 = __builtin_bit_cast(s8b, (u4v){pk[0], pk[1], pk[2], pk[3]});
        s8b pf1 = __builtin_bit_cast(s8b, (u4v){pk[4], pk[5], pk[6], pk[7]});

        // (C) O^T += V^T P^T, V frags from LDS
#pragma unroll
        for (int c = 0; c < 8; ++c) {
            s8b v0 = *(const s8b*)(Vbuf + (2 * c) * 512);
            s8b v1 = *(const s8b*)(Vbuf + (2 * c + 1) * 512);
            acc[c] = MFMA32(v0, pf0, acc[c]);
            acc[c] = MFMA32(v1, pf1, acc[c]);
        }

        // barrier: implicit vmcnt(0) drains tile t+1's DMA (issued a full phase ago)
        __syncthreads();

        // prefetch tile t+2 into the buffer we just finished reading
        {
            const int tp = (t + 2 < tend) ? t + 2 : tend - 1;
            const s8b* gp = gseg + (size_t)tp * 1024;
            short* lp = lseg + cur * 16384;
#pragma unroll
            for (int i = 0; i < 8; ++i) dma16(gp + i * 64, lp + i * 512);
        }
    }

    // finalize l (other half-lane holds the other 16 keys of each q-column)
    lsum += __shfl_xor(lsum, 32);

    // write bf16 unnormalized partials + fp32 l
    const int qrow = q0 + 32 * w + lc;
    const size_t sbase = (size_t)s * NEWB;
    short* op_row = OPb + (sbase + qrow) * DHEAD;
#pragma unroll
    for (int c = 0; c < 8; ++c)
#pragma unroll
        for (int g = 0; g < 4; ++g) {
            s4b o4;
            o4[0] = f2bf(acc[c][4 * g]);
            o4[1] = f2bf(acc[c][4 * g + 1]);
            o4[2] = f2bf(acc[c][4 * g + 2]);
            o4[3] = f2bf(acc[c][4 * g + 3]);
            *(s4b*)(op_row + 32 * c + 8 * g + 4 * h) = o4;
        }
    if (h == 0) L[sbase + qrow] = lsum;
}

// ---------- kernel 3: split-K combine (bf16 partials, fp32 l) ----------
__global__ void combine_kernel(const short* __restrict__ OPb, const float* __restrict__ L,
                               float* __restrict__ out, int SPLIT) {
    const int row = blockIdx.x;
    const int col = threadIdx.x;
    float num = 0.f, den = 0.f;
    for (int s = 0; s < SPLIT; ++s) {
        size_t r = (size_t)s * NEWB + row;
        unsigned u = (unsigned)(unsigned short)OPb[r * DHEAD + col];
        num += __uint_as_float(u << 16);
        den += L[r];
    }
    out[(size_t)row * DHEAD + col] = num / den;
}

// ---------- launch ----------
extern "C" void kernel_launch(void* const* d_in, const int* in_sizes, int n_in,
                              void* d_out, int out_size, void* d_ws, size_t ws_size,
                              hipStream_t stream) {
    const float* q  = (const float*)d_in[0];
    const float* kn = (const float*)d_in[1];
    const float* vn = (const float*)d_in[2];
    const float* Kc = (const float*)d_in[3];
    const float* Vc = (const float*)d_in[4];
    float* out = (float*)d_out;

    char* ws = (char*)d_ws;
    const size_t KB_BYTES = (size_t)NTOTAL * DHEAD * 2;   // 9,437,184 per array
    s8b* Ksw = (s8b*)(ws);
    s8b* Vsw = (s8b*)(ws + KB_BYTES);
    const size_t PART_BASE = 2 * KB_BYTES;

    const size_t per_split = (size_t)NEWB * DHEAD * 2 + (size_t)NEWB * 4;  // bf16 OP + fp32 L
    size_t avail = (ws_size > PART_BASE) ? (ws_size - PART_BASE) : 0;
    int SPLIT = (int)(avail / per_split);
    if (SPLIT > 32) SPLIT = 32;    // grid 512 = 2 blocks/CU
    if (SPLIT < 1)  SPLIT = 1;

    short* OPb = (short*)(ws + PART_BASE);
    float* L   = (float*)(ws + PART_BASE + (size_t)SPLIT * NEWB * DHEAD * 2);

    cvt_kernel<<<dim3(NTILES, 2), 256, 0, stream>>>(Kc, kn, Vc, vn, Ksw, Vsw);
    attn_kernel<<<16 * SPLIT, 256, 0, stream>>>(q, Ksw, Vsw, OPb, L, SPLIT);
    combine_kernel<<<NEWB, 256, 0, stream>>>(OPb, L, out, SPLIT);
}